// Round 3
// baseline (38.499 us; speedup 1.0000x reference)
//
#include <hip/hip_runtime.h>
#include <math.h>

#define TT 512
#define DD 256
#define BIGF 9999.0f
#define KK 8

// ws layout (bytes)
#define HT_OFF    0          // float ht[DD][TT]   512 KB  transposed H
#define A_OFF     524288     // float a[TT]
#define B_OFF     526336     // float b[TT]
#define MB_OFF    528384     // ull   mb[TT][4]
#define MSEP_OFF  544768     // float msep[TT]
#define RLOSS_OFF 546816     // float rloss[TT]
#define CNT_OFF   548864     // int   counter

__global__ __launch_bounds__(256) void prep_kernel(
    const float* __restrict__ X, const float* __restrict__ H,
    const float* __restrict__ C, const int* __restrict__ M,
    float* __restrict__ ht, float* __restrict__ A, float* __restrict__ B,
    unsigned long long* __restrict__ MB, float* __restrict__ MSEP,
    int* __restrict__ CNT) {
  const int i = blockIdx.x;
  const int d = threadIdx.x;
  if (i == 0 && d == 0) *CNT = 0;  // re-arm the last-block counter each call
  const int idx = i * DD + d;
  const float x = X[idx], h = H[idx], c = C[idx];
  const int m = M[idx];
  ht[d * TT + i] = h;  // transpose write (scattered, L2-absorbed, once)
  const float e = m ? (x - h + c) : 0.0f;
  float pm = e * e;
  float ph = h;
  float ph2 = h * h;
#pragma unroll
  for (int s = 1; s < 64; s <<= 1) {
    pm  += __shfl_xor(pm, s);
    ph  += __shfl_xor(ph, s);
    ph2 += __shfl_xor(ph2, s);
  }
  const unsigned long long bal = __ballot(m != 0);
  __shared__ float sm[4], sh[4], sh2[4];
  const int wid = d >> 6, lane = d & 63;
  if (lane == 0) {
    sm[wid] = pm; sh[wid] = ph; sh2[wid] = ph2;
    MB[i * 4 + wid] = bal;
  }
  __syncthreads();
  if (d == 0) {
    A[i] = sh[0] + sh[1] + sh[2] + sh[3];
    B[i] = sh2[0] + sh2[1] + sh2[2] + sh2[3];
    MSEP[i] = sm[0] + sm[1] + sm[2] + sm[3];
  }
}

// 256 blocks x 256 threads. Block owns 2 i-rows x all 512 j; thread t owns
// j = {2t, 2t+1}. Register outer product over transposed H; no LDS in the
// hot loop. Last-arriving block performs the (fixed-order) final reduction.
__global__ __launch_bounds__(256) void score_kernel(
    const float* __restrict__ ht, const float* __restrict__ A,
    const float* __restrict__ B, const unsigned long long* __restrict__ MB,
    const float* __restrict__ MSEP, float* __restrict__ RLOSS,
    int* __restrict__ CNT, float* __restrict__ out) {
  __shared__ float dl[2][TT];
  __shared__ float nrm[2][TT];
  const int i0 = blockIdx.x * 2;
  const int t = threadIdx.x;

  float a00 = 0.f, a01 = 0.f, a10 = 0.f, a11 = 0.f;  // [row][jj]
  const float* __restrict__ pi = ht + i0;
  const float* __restrict__ pj = ht + 2 * t;
#pragma unroll 16
  for (int d = 0; d < DD; ++d) {
    const float2 hi = *(const float2*)(pi + d * TT);   // uniform (L1-shared)
    const float2 hj = *(const float2*)(pj + d * TT);   // coalesced 512B/wave
    a00 += hi.x * hj.x; a01 += hi.x * hj.y;
    a10 += hi.y * hj.x; a11 += hi.y * hj.y;
  }

  const float ai0 = A[i0], ai1 = A[i0 + 1];
  const float bi0 = B[i0], bi1 = B[i0 + 1];
  unsigned long long mi[2][4];
#pragma unroll
  for (int r = 0; r < 2; ++r)
#pragma unroll
    for (int c = 0; c < 4; ++c) mi[r][c] = MB[(i0 + r) * 4 + c];

#pragma unroll
  for (int jj = 0; jj < 2; ++jj) {
    const int j = 2 * t + jj;
    const float aj = A[j], bj = B[j];
    const unsigned long long m0 = MB[j * 4 + 0], m1 = MB[j * 4 + 1],
                             m2 = MB[j * 4 + 2], m3 = MB[j * 4 + 3];
    const float dot0 = jj ? a01 : a00;
    const float dot1 = jj ? a11 : a10;
    {
      const float s2 = bi0 + bj - 2.0f * dot0;
      const float s1 = ai0 - aj;
      const float var = (s2 - s1 * s1 * (1.0f / DD)) * (1.0f / (DD - 1));
      const bool diff = (m0 != mi[0][0]) | (m1 != mi[0][1]) |
                        (m2 != mi[0][2]) | (m3 != mi[0][3]);
      const bool valid = diff && (j != i0);
      dl[0][j] = valid ? sqrtf(fmaxf(var, 0.0f)) : BIGF;
      nrm[0][j] = sqrtf(fmaxf(s2, 0.0f));
    }
    {
      const float s2 = bi1 + bj - 2.0f * dot1;
      const float s1 = ai1 - aj;
      const float var = (s2 - s1 * s1 * (1.0f / DD)) * (1.0f / (DD - 1));
      const bool diff = (m0 != mi[1][0]) | (m1 != mi[1][1]) |
                        (m2 != mi[1][2]) | (m3 != mi[1][3]);
      const bool valid = diff && (j != i0 + 1);
      dl[1][j] = valid ? sqrtf(fmaxf(var, 0.0f)) : BIGF;
      nrm[1][j] = sqrtf(fmaxf(s2, 0.0f));
    }
  }
  __syncthreads();

  // waves 0,1: per-row iterative top-8 smallest (lowest-index tie-break)
  const int w = t >> 6, lane = t & 63;
  if (w < 2) {
    float cv[8];
#pragma unroll
    for (int c = 0; c < 8; ++c) cv[c] = dl[w][lane + 64 * c];

    float kv[KK];
    int ki[KK];
#pragma unroll
    for (int k = 0; k < KK; ++k) {
      float bv = cv[0];
      int bc = 0;
#pragma unroll
      for (int c = 1; c < 8; ++c) {
        if (cv[c] < bv) { bv = cv[c]; bc = c; }
      }
      int bidx = lane + 64 * bc;
#pragma unroll
      for (int s = 1; s < 64; s <<= 1) {
        const float ov = __shfl_xor(bv, s);
        const int oi = __shfl_xor(bidx, s);
        if (ov < bv || (ov == bv && oi < bidx)) { bv = ov; bidx = oi; }
      }
      kv[k] = bv;
      ki[k] = bidx;
      const int csel = bidx >> 6;
      const bool mine = (bidx & 63) == lane;
#pragma unroll
      for (int c = 0; c < 8; ++c) {
        if (mine && c == csel) cv[c] = BIGF;
      }
    }
    float wsum = 0.0f, rl = 0.0f;
#pragma unroll
    for (int k = 0; k < KK; ++k) {
      const float e = expf(kv[0] - kv[k]);  // kv[0] = min score
      wsum += e;
      rl += e * nrm[w][ki[k]];
    }
    if (lane == 0) {
      __hip_atomic_store(&RLOSS[i0 + w], rl / wsum, __ATOMIC_RELAXED,
                         __HIP_MEMORY_SCOPE_AGENT);
      __threadfence();  // device-scope release of the row result
    }
  }
  __syncthreads();

  __shared__ int lastflag;
  if (t == 0) {
    const int old = __hip_atomic_fetch_add(CNT, 1, __ATOMIC_ACQ_REL,
                                           __HIP_MEMORY_SCOPE_AGENT);
    lastflag = (old == (int)gridDim.x - 1);
  }
  __syncthreads();
  if (lastflag) {
    // fixed-order, bitwise-deterministic final sum of 512 + 512 values
    float v = 0.0f;
#pragma unroll
    for (int q = 0; q < 2; ++q) {
      const int r = t + 256 * q;
      v += __hip_atomic_load(&RLOSS[r], __ATOMIC_RELAXED,
                             __HIP_MEMORY_SCOPE_AGENT);
      v += MSEP[r];
    }
#pragma unroll
    for (int s = 1; s < 64; s <<= 1) v += __shfl_xor(v, s);
    __shared__ float sp[4];
    if ((t & 63) == 0) sp[t >> 6] = v;
    __syncthreads();
    if (t == 0) out[0] = sp[0] + sp[1] + sp[2] + sp[3];
  }
}

extern "C" void kernel_launch(void* const* d_in, const int* in_sizes, int n_in,
                              void* d_out, int out_size, void* d_ws, size_t ws_size,
                              hipStream_t stream) {
  const float* X = (const float*)d_in[0];
  const float* H = (const float*)d_in[1];
  const float* C = (const float*)d_in[2];
  const int* M = (const int*)d_in[3];
  float* out = (float*)d_out;

  char* ws = (char*)d_ws;
  float* ht = (float*)(ws + HT_OFF);
  float* A = (float*)(ws + A_OFF);
  float* B = (float*)(ws + B_OFF);
  unsigned long long* MB = (unsigned long long*)(ws + MB_OFF);
  float* MSEP = (float*)(ws + MSEP_OFF);
  float* RLOSS = (float*)(ws + RLOSS_OFF);
  int* CNT = (int*)(ws + CNT_OFF);

  prep_kernel<<<TT, DD, 0, stream>>>(X, H, C, M, ht, A, B, MB, MSEP, CNT);
  score_kernel<<<TT / 2, 256, 0, stream>>>(ht, A, B, MB, MSEP, RLOSS, CNT, out);
}